// Round 1
// baseline (105.830 us; speedup 1.0000x reference)
//
#include <hip/hip_runtime.h>
#include <math.h>

// Sparsemax along last dim, rows of d=2048, fp32.
// One wave (64 lanes) per row; row lives entirely in registers (32 floats/lane).
// tau found via Michelot's algorithm (exact, no sort):
//   active = all; repeat { tau = (sum(active)-1)/|active|; active = {x > tau} }
//   until |active| unchanged.  Monotone tau + nested sets => exact finite term.
// Output: max(x - max(x) - tau, 0).

constexpr int D      = 2048;
constexpr int LANES  = 64;
constexpr int PER    = D / LANES;   // 32 elements per lane
constexpr int WAVES  = 4;           // waves (rows) per block
constexpr int BLOCK  = WAVES * LANES;

__global__ __launch_bounds__(BLOCK)
void sparsemax_kernel(const float* __restrict__ X, float* __restrict__ Y, int nrows)
{
    const int wid  = threadIdx.x >> 6;
    const int lane = threadIdx.x & 63;
    const int row  = blockIdx.x * WAVES + wid;
    if (row >= nrows) return;

    const float4* __restrict__ px = reinterpret_cast<const float4*>(X) + (size_t)row * (D / 4);
    float4*       __restrict__ py = reinterpret_cast<float4*>(Y)       + (size_t)row * (D / 4);

    // ---- load row: lane reads float4 at [j*64 + lane] -> fully coalesced ----
    float a[PER];
    #pragma unroll
    for (int j = 0; j < PER / 4; ++j) {
        float4 v = px[j * LANES + lane];
        a[4*j+0] = v.x; a[4*j+1] = v.y; a[4*j+2] = v.z; a[4*j+3] = v.w;
    }

    // ---- row max and row sum (one butterfly pass for both) ----
    float mx = a[0], sm = 0.0f;
    #pragma unroll
    for (int i = 0; i < PER; ++i) { mx = fmaxf(mx, a[i]); sm += a[i]; }
    #pragma unroll
    for (int off = 32; off >= 1; off >>= 1) {
        mx  = fmaxf(mx, __shfl_xor(mx, off));
        sm += __shfl_xor(sm, off);
    }

    // shift for numerical stability (reference does the same)
    #pragma unroll
    for (int i = 0; i < PER; ++i) a[i] -= mx;

    // ---- Michelot iteration ----
    // tau0 from the full set; shifted sum = sm - D*mx
    float tau   = (sm - (float)D * mx - 1.0f) * (1.0f / (float)D);
    int   cprev = D;

    for (int it = 0; it < D; ++it) {          // cap = D (guaranteed termination)
        float s = 0.0f, c = 0.0f;
        #pragma unroll
        for (int i = 0; i < PER; ++i) {
            if (a[i] > tau) { s += a[i]; c += 1.0f; }
        }
        #pragma unroll
        for (int off = 32; off >= 1; off >>= 1) {
            s += __shfl_xor(s, off);
            c += __shfl_xor(c, off);
        }
        tau = (s - 1.0f) / c;                 // c >= 1 always (max elem, 0 > tau)
        int ci = (int)c;
        if (ci == cprev) break;               // set unchanged -> tau is exact
        cprev = ci;
    }

    // ---- write output ----
    #pragma unroll
    for (int j = 0; j < PER / 4; ++j) {
        float4 v;
        v.x = fmaxf(a[4*j+0] - tau, 0.0f);
        v.y = fmaxf(a[4*j+1] - tau, 0.0f);
        v.z = fmaxf(a[4*j+2] - tau, 0.0f);
        v.w = fmaxf(a[4*j+3] - tau, 0.0f);
        py[j * LANES + lane] = v;
    }
}

extern "C" void kernel_launch(void* const* d_in, const int* in_sizes, int n_in,
                              void* d_out, int out_size, void* d_ws, size_t ws_size,
                              hipStream_t stream)
{
    const float* X = reinterpret_cast<const float*>(d_in[0]);
    float*       Y = reinterpret_cast<float*>(d_out);
    const int nrows = in_sizes[0] / D;                 // 32768
    const int grid  = (nrows + WAVES - 1) / WAVES;     // 8192 blocks
    sparsemax_kernel<<<grid, BLOCK, 0, stream>>>(X, Y, nrows);
}

// Round 3
// 95.318 us; speedup vs baseline: 1.1103x; 1.1103x over previous
//
#include <hip/hip_runtime.h>
#include <math.h>

// Sparsemax along last dim, rows of d=2048, fp32.
// One wave (64 lanes) per row; row lives entirely in registers (32 floats/lane).
// tau via Michelot's algorithm, started from the exact a-priori bound tau* >= -1
// (shifted max = 0, and p_max = -tau* <= 1). S0 = {a > -1} is a superset of the
// support, so the iteration is exact and converges in ~3 scans on Gaussian data.

constexpr int D      = 2048;
constexpr int LANES  = 64;
constexpr int PER    = D / LANES;   // 32 elements per lane
constexpr int WAVES  = 4;           // waves (rows) per block
constexpr int BLOCK  = WAVES * LANES;

typedef float f32x4 __attribute__((ext_vector_type(4)));  // native vector: OK for nontemporal builtins

__global__ __launch_bounds__(BLOCK)
void sparsemax_kernel(const float* __restrict__ X, float* __restrict__ Y, int nrows)
{
    const int wid  = threadIdx.x >> 6;
    const int lane = threadIdx.x & 63;
    const int row  = blockIdx.x * WAVES + wid;
    if (row >= nrows) return;

    const f32x4* __restrict__ px = reinterpret_cast<const f32x4*>(X) + (size_t)row * (D / 4);
    f32x4*       __restrict__ py = reinterpret_cast<f32x4*>(Y)       + (size_t)row * (D / 4);

    // ---- load row (nontemporal, fully coalesced: lane reads float4 at [j*64+lane]) ----
    float a[PER];
    #pragma unroll
    for (int j = 0; j < PER / 4; ++j) {
        f32x4 v = __builtin_nontemporal_load(&px[j * LANES + lane]);
        a[4*j+0] = v.x; a[4*j+1] = v.y; a[4*j+2] = v.z; a[4*j+3] = v.w;
    }

    // ---- row max (single butterfly) ----
    float mx = a[0];
    #pragma unroll
    for (int i = 1; i < PER; ++i) mx = fmaxf(mx, a[i]);
    #pragma unroll
    for (int off = 32; off >= 1; off >>= 1)
        mx = fmaxf(mx, __shfl_xor(mx, off));

    // shift for numerical stability (max element becomes 0)
    #pragma unroll
    for (int i = 0; i < PER; ++i) a[i] -= mx;

    // ---- Michelot from S0 = {a > -1}  (tau* >= -1 always) ----
    float tau   = -1.0f;
    int   cprev = -1;

    for (int it = 0; it < D; ++it) {          // cap for guaranteed termination
        float s = 0.0f, c = 0.0f;
        #pragma unroll
        for (int i = 0; i < PER; ++i) {
            if (a[i] > tau) { s += a[i]; c += 1.0f; }
        }
        #pragma unroll
        for (int off = 32; off >= 1; off >>= 1) {
            s += __shfl_xor(s, off);
            c += __shfl_xor(c, off);
        }
        tau = (s - 1.0f) / c;                 // c >= 1 always (max elem 0 > -1)
        int ci = (int)c;
        if (ci == cprev) break;               // same count + nested sets -> same set -> exact
        cprev = ci;
    }

    // ---- write output (nontemporal) ----
    #pragma unroll
    for (int j = 0; j < PER / 4; ++j) {
        f32x4 v;
        v.x = fmaxf(a[4*j+0] - tau, 0.0f);
        v.y = fmaxf(a[4*j+1] - tau, 0.0f);
        v.z = fmaxf(a[4*j+2] - tau, 0.0f);
        v.w = fmaxf(a[4*j+3] - tau, 0.0f);
        __builtin_nontemporal_store(v, &py[j * LANES + lane]);
    }
}

extern "C" void kernel_launch(void* const* d_in, const int* in_sizes, int n_in,
                              void* d_out, int out_size, void* d_ws, size_t ws_size,
                              hipStream_t stream)
{
    const float* X = reinterpret_cast<const float*>(d_in[0]);
    float*       Y = reinterpret_cast<float*>(d_out);
    const int nrows = in_sizes[0] / D;                 // 32768
    const int grid  = (nrows + WAVES - 1) / WAVES;     // 8192 blocks
    sparsemax_kernel<<<grid, BLOCK, 0, stream>>>(X, Y, nrows);
}

// Round 4
// 93.658 us; speedup vs baseline: 1.1300x; 1.0177x over previous
//
#include <hip/hip_runtime.h>
#include <math.h>

// Sparsemax along last dim, rows of d=2048, fp32.
// One wave per row; row lives in registers (32 floats/lane). tau via Michelot
// from the exact a-priori bound tau* >= -1 (shifted max = 0, p_max <= 1).
// Unshifted formulation: scan x > t with t = mx + tau; shifted sum = s - c*mx.
// Output: max(x - (mx + tau), 0).

constexpr int D      = 2048;
constexpr int LANES  = 64;
constexpr int PER    = D / LANES;   // 32 elements per lane
constexpr int WAVES  = 4;           // waves (rows) per block
constexpr int BLOCK  = WAVES * LANES;

typedef float f32x4 __attribute__((ext_vector_type(4)));

__global__ __launch_bounds__(BLOCK, 8)   // 8 waves/EU -> VGPR <= 64
void sparsemax_kernel(const float* __restrict__ X, float* __restrict__ Y, int nrows)
{
    const int wid  = threadIdx.x >> 6;
    const int lane = threadIdx.x & 63;
    const int row  = blockIdx.x * WAVES + wid;
    if (row >= nrows) return;

    const f32x4* __restrict__ px = reinterpret_cast<const f32x4*>(X) + (size_t)row * (D / 4);
    f32x4*       __restrict__ py = reinterpret_cast<f32x4*>(Y)       + (size_t)row * (D / 4);

    // ---- load row (nontemporal, coalesced: lane reads float4 at [j*64+lane]) ----
    float a[PER];
    #pragma unroll
    for (int j = 0; j < PER / 4; ++j) {
        f32x4 v = __builtin_nontemporal_load(&px[j * LANES + lane]);
        a[4*j+0] = v.x; a[4*j+1] = v.y; a[4*j+2] = v.z; a[4*j+3] = v.w;
    }

    // ---- row max (single butterfly) ----
    float mx = a[0];
    #pragma unroll
    for (int i = 1; i < PER; ++i) mx = fmaxf(mx, a[i]);
    #pragma unroll
    for (int off = 32; off >= 1; off >>= 1)
        mx = fmaxf(mx, __shfl_xor(mx, off));

    // ---- Michelot in unshifted domain; S0 = {x > mx - 1}  (tau* >= -1) ----
    float tau   = -1.0f;
    int   cprev = -1;

    for (int it = 0; it < D; ++it) {              // cap for guaranteed termination
        const float t = mx + tau;                 // unshifted threshold
        float s = 0.0f, c = 0.0f;
        #pragma unroll
        for (int i = 0; i < PER; ++i) {
            if (a[i] > t) { s += a[i]; c += 1.0f; }
        }
        #pragma unroll
        for (int off = 32; off >= 1; off >>= 1) {
            s += __shfl_xor(s, off);
            c += __shfl_xor(c, off);
        }
        // shifted sum = s - c*mx ; tau = (shifted_sum - 1)/c via fast rcp
        tau = (s - c * mx - 1.0f) * __builtin_amdgcn_rcpf(c);
        int ci = (int)c;
        if (ci == cprev) break;                   // same count + nested -> exact
        cprev = ci;
    }

    // ---- write output: max(x - T, 0), T = mx + tau (nontemporal) ----
    const float T = mx + tau;
    #pragma unroll
    for (int j = 0; j < PER / 4; ++j) {
        f32x4 v;
        v.x = fmaxf(a[4*j+0] - T, 0.0f);
        v.y = fmaxf(a[4*j+1] - T, 0.0f);
        v.z = fmaxf(a[4*j+2] - T, 0.0f);
        v.w = fmaxf(a[4*j+3] - T, 0.0f);
        __builtin_nontemporal_store(v, &py[j * LANES + lane]);
    }
}

extern "C" void kernel_launch(void* const* d_in, const int* in_sizes, int n_in,
                              void* d_out, int out_size, void* d_ws, size_t ws_size,
                              hipStream_t stream)
{
    const float* X = reinterpret_cast<const float*>(d_in[0]);
    float*       Y = reinterpret_cast<float*>(d_out);
    const int nrows = in_sizes[0] / D;                 // 32768
    const int grid  = (nrows + WAVES - 1) / WAVES;     // 8192 blocks
    sparsemax_kernel<<<grid, BLOCK, 0, stream>>>(X, Y, nrows);
}